// Round 1
// baseline (1808.779 us; speedup 1.0000x reference)
//
#include <hip/hip_runtime.h>

#define Bn 4
#define Cn 256
#define C8 32
#define Hn 64
#define Wn 64
#define HWn 4096

// ---------------------------------------------------------------------------
// K0: weight prep — transpose + convert so inner loops read contiguous,
// wave-uniform (scalar-loadable) weight rows.
//   Wq (32x256) -> Wqt[c*32+o] (double), same for Wk; bq,bk -> double
//   Wv (256x256) -> Wvt[c*256+o] (float)
//   Wf (256x512x3x3) -> Wft[(ci*9+tap)*256 + o] (float)
// ---------------------------------------------------------------------------
__global__ void prep_w(const float* __restrict__ Wq, const float* __restrict__ bq,
                       const float* __restrict__ Wk, const float* __restrict__ bk,
                       const float* __restrict__ Wv, const float* __restrict__ Wf,
                       double* __restrict__ Wqt, double* __restrict__ bqd,
                       double* __restrict__ Wkt, double* __restrict__ bkd,
                       float* __restrict__ Wvt, float* __restrict__ Wft) {
  size_t t = (size_t)blockIdx.x * 256 + threadIdx.x;
  if (t < 8192) {
    int o = (int)(t / 256), c = (int)(t % 256);
    Wqt[(size_t)c * 32 + o] = (double)Wq[t];
    Wkt[(size_t)c * 32 + o] = (double)Wk[t];
  }
  if (t < 32) { bqd[t] = (double)bq[t]; bkd[t] = (double)bk[t]; }
  if (t < 65536) {
    int o = (int)(t / 256), c = (int)(t % 256);
    Wvt[(size_t)c * 256 + o] = Wv[t];
  }
  if (t < (size_t)256 * 512 * 9) {
    int o = (int)(t / 4608);
    int r = (int)(t % 4608);
    int ci = r / 9, tap = r % 9;
    Wft[((size_t)ci * 9 + tap) * 256 + o] = Wf[t];
  }
}

// ---------------------------------------------------------------------------
// K1: q/k projection in fp64. z=0 -> q from cross_x, z=1 -> k from front_x.
// Output layout (b, j, o): out[(b*HW + j)*32 + o]  (j-major for K2 access).
// ---------------------------------------------------------------------------
__global__ __launch_bounds__(256) void proj_qk(
    const float* __restrict__ cross_x, const float* __restrict__ front_x,
    const double* __restrict__ Wqt, const double* __restrict__ bqd,
    const double* __restrict__ Wkt, const double* __restrict__ bkd,
    double* __restrict__ qd, double* __restrict__ kd) {
  int j = blockIdx.x * 256 + threadIdx.x;
  int b = blockIdx.y;
  int z = blockIdx.z;
  const float* x = (z == 0) ? cross_x : front_x;
  const double* Wt = (z == 0) ? Wqt : Wkt;
  const double* bd = (z == 0) ? bqd : bkd;
  double* outp = (z == 0) ? qd : kd;

  const float* xb = x + (size_t)b * Cn * HWn + j;
  double acc[C8];
#pragma unroll
  for (int o = 0; o < C8; ++o) acc[o] = bd[o];
  for (int c = 0; c < Cn; ++c) {
    double xv = (double)xb[(size_t)c * HWn];
    const double* wrow = Wt + (size_t)c * C8;  // uniform, contiguous -> s_load
#pragma unroll
    for (int o = 0; o < C8; ++o) acc[o] += wrow[o] * xv;
  }
  double* op = outp + ((size_t)b * HWn + j) * C8;
#pragma unroll
  for (int o = 0; o < C8; ++o) op[o] = acc[o];
}

// ---------------------------------------------------------------------------
// K2: energy[b,i,j] = sum_o k[b,i,o]*q[b,j,o]; per-j max+argmax over i (fp64).
// Block: 512 threads = 8 waves; lane -> j (64 per block); wave -> i stride 8.
// k-tile (64 i x 32 o doubles = 16KB) staged in LDS; per-i reads are
// wave-uniform -> LDS broadcast. Strict > keeps first occurrence; cross-wave
// merge tie-breaks on smaller i (matches jnp.argmax).
// ---------------------------------------------------------------------------
__global__ __launch_bounds__(512) void energy_max(
    const double* __restrict__ qd, const double* __restrict__ kd,
    float* __restrict__ star, int* __restrict__ argb) {
  int b = blockIdx.y;
  int j0 = blockIdx.x * 64;
  int tid = threadIdx.x;
  int lane = tid & 63;
  int wv = tid >> 6;  // 0..7
  int j = j0 + lane;

  __shared__ double kt[64][C8];    // 16 KB
  __shared__ double bestvS[8][64];
  __shared__ int bestiS[8][64];

  double qj[C8];
  const double* qp = qd + ((size_t)b * HWn + j) * C8;
#pragma unroll
  for (int o = 0; o < C8; ++o) qj[o] = qp[o];

  double best = -1.0e300;
  int bidx = 0;

  for (int it = 0; it < HWn; it += 64) {
    __syncthreads();
    {
      const double* src = kd + ((size_t)b * HWn + it) * C8;
      double* dst = &kt[0][0];
      for (int u = tid; u < 64 * C8; u += 512) dst[u] = src[u];
    }
    __syncthreads();
#pragma unroll 1
    for (int m = wv; m < 64; m += 8) {
      double s0 = 0.0, s1 = 0.0;
#pragma unroll
      for (int o = 0; o < C8; o += 2) {
        s0 += kt[m][o] * qj[o];
        s1 += kt[m][o + 1] * qj[o + 1];
      }
      double s = s0 + s1;
      int ig = it + m;
      if (s > best) { best = s; bidx = ig; }
    }
  }
  bestvS[wv][lane] = best;
  bestiS[wv][lane] = bidx;
  __syncthreads();
  if (wv == 0) {
#pragma unroll
    for (int w2 = 1; w2 < 8; ++w2) {
      double s = bestvS[w2][lane];
      int ig = bestiS[w2][lane];
      if (s > best || (s == best && ig < bidx)) { best = s; bidx = ig; }
    }
    star[(size_t)b * HWn + j] = (float)best;
    argb[(size_t)b * HWn + j] = bidx;
  }
}

// ---------------------------------------------------------------------------
// K3: v projection (fp32). 64 output channels per thread; weights via
// uniform contiguous scalar loads from transposed Wvt.
// ---------------------------------------------------------------------------
__global__ __launch_bounds__(256) void proj_v(
    const float* __restrict__ x, const float* __restrict__ Wvt,
    const float* __restrict__ bv, float* __restrict__ v) {
  int j = blockIdx.x * 256 + threadIdx.x;
  int b = blockIdx.y;
  int o0 = blockIdx.z * 64;
  const float* xb = x + (size_t)b * Cn * HWn + j;
  float acc[64];
#pragma unroll
  for (int o = 0; o < 64; ++o) acc[o] = bv[o0 + o];
  for (int c = 0; c < Cn; ++c) {
    float xv = xb[(size_t)c * HWn];
    const float* wrow = Wvt + (size_t)c * 256 + o0;  // uniform -> s_load
#pragma unroll
    for (int o = 0; o < 64; ++o) acc[o] += wrow[o] * xv;
  }
  float* vp = v + ((size_t)b * Cn + o0) * HWn + j;
#pragma unroll
  for (int o = 0; o < 64; ++o) vp[(size_t)o * HWn] = acc[o];
}

// ---------------------------------------------------------------------------
// K4: hard gather  T[b,c,j] = v[b,c,arg[b,j]]
// ---------------------------------------------------------------------------
__global__ __launch_bounds__(256) void gather_T(
    const float* __restrict__ v, const int* __restrict__ argb,
    float* __restrict__ T) {
  int j = blockIdx.x * 256 + threadIdx.x;
  int b = blockIdx.y;
  int aj = argb[(size_t)b * HWn + j];
  const float* vb = v + (size_t)b * Cn * HWn;
  float* Tb = T + (size_t)b * Cn * HWn;
  for (int c = 0; c < Cn; ++c) Tb[(size_t)c * HWn + j] = vb[(size_t)c * HWn + aj];
}

// ---------------------------------------------------------------------------
// K5: 3x3 SAME conv over cat(front_x, T) + epilogue out = fx + (conv+bf)*S.
// Block: 256 threads = 16x16 spatial tile; 32 output channels per thread.
// Input tile (18x18) per ci staged in LDS; weights via uniform scalar loads
// from transposed Wft.
// ---------------------------------------------------------------------------
__global__ __launch_bounds__(256) void conv3_ep(
    const float* __restrict__ fx, const float* __restrict__ T,
    const float* __restrict__ Wft, const float* __restrict__ bf,
    const float* __restrict__ star, float* __restrict__ out) {
  int b = blockIdx.y;
  int o0 = blockIdx.z * 32;
  int tile = blockIdx.x;  // 0..15
  int ty0 = (tile >> 2) * 16, tx0 = (tile & 3) * 16;
  int tid = threadIdx.x;
  int ty = tid >> 4, tx = tid & 15;
  int y = ty0 + ty, x = tx0 + tx;

  __shared__ float tileS[18][20];  // +pad cols vs bank conflicts

  float acc[32];
#pragma unroll
  for (int o = 0; o < 32; ++o) acc[o] = bf[o0 + o];

  for (int ci = 0; ci < 2 * Cn; ++ci) {
    const float* src = (ci < Cn) ? (fx + (size_t)(b * Cn + ci) * HWn)
                                 : (T + (size_t)(b * Cn + (ci - Cn)) * HWn);
    __syncthreads();
    for (int u = tid; u < 18 * 18; u += 256) {
      int r = u / 18, cc = u % 18;
      int gy = ty0 - 1 + r, gx = tx0 - 1 + cc;
      float val = 0.f;
      if (gy >= 0 && gy < Hn && gx >= 0 && gx < Wn) val = src[gy * Wn + gx];
      tileS[r][cc] = val;
    }
    __syncthreads();

    float tv[9];
#pragma unroll
    for (int ky = 0; ky < 3; ++ky)
#pragma unroll
      for (int kx = 0; kx < 3; ++kx) tv[ky * 3 + kx] = tileS[ty + ky][tx + kx];

#pragma unroll
    for (int tap = 0; tap < 9; ++tap) {
      const float* wt = Wft + ((size_t)ci * 9 + tap) * 256 + o0;  // uniform
      float t0 = tv[tap];
#pragma unroll
      for (int o = 0; o < 32; ++o) acc[o] += t0 * wt[o];
    }
  }

  float S = star[(size_t)b * HWn + y * Wn + x];
  size_t pix = (size_t)y * Wn + x;
#pragma unroll
  for (int o = 0; o < 32; ++o) {
    size_t idx = (size_t)(b * Cn + o0 + o) * HWn + pix;
    out[idx] = fx[idx] + acc[o] * S;
  }
}

// ---------------------------------------------------------------------------
extern "C" void kernel_launch(void* const* d_in, const int* in_sizes, int n_in,
                              void* d_out, int out_size, void* d_ws, size_t ws_size,
                              hipStream_t stream) {
  const float* front_x   = (const float*)d_in[0];
  const float* cross_x   = (const float*)d_in[1];
  const float* front_hat = (const float*)d_in[2];
  const float* Wq = (const float*)d_in[3];
  const float* bq = (const float*)d_in[4];
  const float* Wk = (const float*)d_in[5];
  const float* bk = (const float*)d_in[6];
  const float* Wv = (const float*)d_in[7];
  const float* bv = (const float*)d_in[8];
  const float* Wf = (const float*)d_in[9];
  const float* bf = (const float*)d_in[10];
  float* out = (float*)d_out;

  char* ws = (char*)d_ws;
  size_t off = 0;
  auto alloc = [&](size_t bytes) -> void* {
    void* p = (void*)(ws + off);
    off += (bytes + 255) & ~(size_t)255;
    return p;
  };
  double* Wqt = (double*)alloc(8192 * sizeof(double));
  double* Wkt = (double*)alloc(8192 * sizeof(double));
  double* bqd = (double*)alloc(32 * sizeof(double));
  double* bkd = (double*)alloc(32 * sizeof(double));
  float*  Wvt = (float*)alloc(65536 * sizeof(float));
  float*  Wft = (float*)alloc((size_t)512 * 9 * 256 * sizeof(float));
  double* qd  = (double*)alloc((size_t)Bn * HWn * C8 * sizeof(double));
  double* kd  = (double*)alloc((size_t)Bn * HWn * C8 * sizeof(double));
  float*  star = (float*)alloc((size_t)Bn * HWn * sizeof(float));
  int*    argb = (int*)alloc((size_t)Bn * HWn * sizeof(int));
  float*  v    = (float*)alloc((size_t)Bn * Cn * HWn * sizeof(float));
  float*  T    = (float*)alloc((size_t)Bn * Cn * HWn * sizeof(float));
  // total ~45 MB of d_ws

  prep_w<<<dim3((256 * 512 * 9 + 255) / 256), dim3(256), 0, stream>>>(
      Wq, bq, Wk, bk, Wv, Wf, Wqt, bqd, Wkt, bkd, Wvt, Wft);

  proj_qk<<<dim3(HWn / 256, Bn, 2), dim3(256), 0, stream>>>(
      cross_x, front_x, Wqt, bqd, Wkt, bkd, qd, kd);

  energy_max<<<dim3(HWn / 64, Bn), dim3(512), 0, stream>>>(qd, kd, star, argb);

  proj_v<<<dim3(HWn / 256, Bn, 4), dim3(256), 0, stream>>>(front_hat, Wvt, bv, v);

  gather_T<<<dim3(HWn / 256, Bn), dim3(256), 0, stream>>>(v, argb, T);

  conv3_ep<<<dim3(16, Bn, 8), dim3(256), 0, stream>>>(front_x, T, Wft, bf, star, out);
}

// Round 2
// 682.184 us; speedup vs baseline: 2.6515x; 2.6515x over previous
//
#include <hip/hip_runtime.h>

#define Bn 4
#define Cn 256
#define C8 32
#define Hn 64
#define Wn 64
#define HWn 4096
#define PADR 66
#define ROWS (HWn + 2 * PADR)   // 4228 padded pixel-rows per batch

typedef __bf16 bf16x8 __attribute__((ext_vector_type(8)));
typedef float floatx4 __attribute__((ext_vector_type(4)));
typedef unsigned short u16x8 __attribute__((ext_vector_type(8)));

__device__ __forceinline__ unsigned short f2bf(float f) {
  union { float f; unsigned int u; } c; c.f = f;
  unsigned int u = c.u;
  return (unsigned short)((u + 0x7FFFu + ((u >> 16) & 1u)) >> 16);  // RNE
}

__device__ __forceinline__ void gl_lds16(const void* g, void* l) {
  __builtin_amdgcn_global_load_lds(
      (__attribute__((address_space(1))) void*)(uintptr_t)g,
      (__attribute__((address_space(3))) void*)(uintptr_t)l, 16, 0, 0);
}

// ---------------------------------------------------------------------------
// K0: weight prep.
//   Wq/Wk (32x256) -> fp64 transposed [c][o]; bq/bk -> fp64
//   Wv (256x256) -> fp32 transposed [c][o]
//   Wf (256,512,3,3) -> bf16 Wfb[tap][o][ci]   (A-operand of conv GEMM)
// ---------------------------------------------------------------------------
__global__ void prep_w(const float* __restrict__ Wq, const float* __restrict__ bq,
                       const float* __restrict__ Wk, const float* __restrict__ bk,
                       const float* __restrict__ Wv, const float* __restrict__ Wf,
                       double* __restrict__ Wqt, double* __restrict__ bqd,
                       double* __restrict__ Wkt, double* __restrict__ bkd,
                       float* __restrict__ Wvt, unsigned short* __restrict__ Wfb) {
  size_t t = (size_t)blockIdx.x * 256 + threadIdx.x;
  if (t < 8192) {
    int o = (int)(t / 256), c = (int)(t % 256);
    Wqt[(size_t)c * 32 + o] = (double)Wq[t];
    Wkt[(size_t)c * 32 + o] = (double)Wk[t];
  }
  if (t < 32) { bqd[t] = (double)bq[t]; bkd[t] = (double)bk[t]; }
  if (t < 65536) {
    int o = (int)(t / 256), c = (int)(t % 256);
    Wvt[(size_t)c * 256 + o] = Wv[t];
  }
  if (t < (size_t)9 * 256 * 512) {
    int tap = (int)(t / (256 * 512));
    int rem = (int)(t % (256 * 512));
    int o = rem / 512, ci = rem % 512;
    Wfb[t] = f2bf(Wf[((size_t)o * 512 + ci) * 9 + tap]);
  }
}

// ---------------------------------------------------------------------------
// K1: q/k projection in fp64 (unchanged).
// ---------------------------------------------------------------------------
__global__ __launch_bounds__(256) void proj_qk(
    const float* __restrict__ cross_x, const float* __restrict__ front_x,
    const double* __restrict__ Wqt, const double* __restrict__ bqd,
    const double* __restrict__ Wkt, const double* __restrict__ bkd,
    double* __restrict__ qd, double* __restrict__ kd) {
  int j = blockIdx.x * 256 + threadIdx.x;
  int b = blockIdx.y;
  int z = blockIdx.z;
  const float* x = (z == 0) ? cross_x : front_x;
  const double* Wt = (z == 0) ? Wqt : Wkt;
  const double* bd = (z == 0) ? bqd : bkd;
  double* outp = (z == 0) ? qd : kd;

  const float* xb = x + (size_t)b * Cn * HWn + j;
  double acc[C8];
#pragma unroll
  for (int o = 0; o < C8; ++o) acc[o] = bd[o];
  for (int c = 0; c < Cn; ++c) {
    double xv = (double)xb[(size_t)c * HWn];
    const double* wrow = Wt + (size_t)c * C8;
#pragma unroll
    for (int o = 0; o < C8; ++o) acc[o] += wrow[o] * xv;
  }
  double* op = outp + ((size_t)b * HWn + j) * C8;
#pragma unroll
  for (int o = 0; o < C8; ++o) op[o] = acc[o];
}

// ---------------------------------------------------------------------------
// K2: energy max/argmax in fp64 (unchanged).
// ---------------------------------------------------------------------------
__global__ __launch_bounds__(512) void energy_max(
    const double* __restrict__ qd, const double* __restrict__ kd,
    float* __restrict__ star, int* __restrict__ argb) {
  int b = blockIdx.y;
  int j0 = blockIdx.x * 64;
  int tid = threadIdx.x;
  int lane = tid & 63;
  int wv = tid >> 6;
  int j = j0 + lane;

  __shared__ double kt[64][C8];
  __shared__ double bestvS[8][64];
  __shared__ int bestiS[8][64];

  double qj[C8];
  const double* qp = qd + ((size_t)b * HWn + j) * C8;
#pragma unroll
  for (int o = 0; o < C8; ++o) qj[o] = qp[o];

  double best = -1.0e300;
  int bidx = 0;

  for (int it = 0; it < HWn; it += 64) {
    __syncthreads();
    {
      const double* src = kd + ((size_t)b * HWn + it) * C8;
      double* dst = &kt[0][0];
      for (int u = tid; u < 64 * C8; u += 512) dst[u] = src[u];
    }
    __syncthreads();
#pragma unroll 1
    for (int m = wv; m < 64; m += 8) {
      double s0 = 0.0, s1 = 0.0;
#pragma unroll
      for (int o = 0; o < C8; o += 2) {
        s0 += kt[m][o] * qj[o];
        s1 += kt[m][o + 1] * qj[o + 1];
      }
      double s = s0 + s1;
      int ig = it + m;
      if (s > best) { best = s; bidx = ig; }
    }
  }
  bestvS[wv][lane] = best;
  bestiS[wv][lane] = bidx;
  __syncthreads();
  if (wv == 0) {
#pragma unroll
    for (int w2 = 1; w2 < 8; ++w2) {
      double s = bestvS[w2][lane];
      int ig = bestiS[w2][lane];
      if (s > best || (s == best && ig < bidx)) { best = s; bidx = ig; }
    }
    star[(size_t)b * HWn + j] = (float)best;
    argb[(size_t)b * HWn + j] = bidx;
  }
}

// ---------------------------------------------------------------------------
// K3: v projection fp32 (unchanged layout: v[b][c][hw]).
// ---------------------------------------------------------------------------
__global__ __launch_bounds__(256) void proj_v(
    const float* __restrict__ x, const float* __restrict__ Wvt,
    const float* __restrict__ bv, float* __restrict__ v) {
  int j = blockIdx.x * 256 + threadIdx.x;
  int b = blockIdx.y;
  int o0 = blockIdx.z * 64;
  const float* xb = x + (size_t)b * Cn * HWn + j;
  float acc[64];
#pragma unroll
  for (int o = 0; o < 64; ++o) acc[o] = bv[o0 + o];
  for (int c = 0; c < Cn; ++c) {
    float xv = xb[(size_t)c * HWn];
    const float* wrow = Wvt + (size_t)c * 256 + o0;
#pragma unroll
    for (int o = 0; o < 64; ++o) acc[o] += wrow[o] * xv;
  }
  float* vp = v + ((size_t)b * Cn + o0) * HWn + j;
#pragma unroll
  for (int o = 0; o < 64; ++o) vp[(size_t)o * HWn] = acc[o];
}

// ---------------------------------------------------------------------------
// K4: transpose front_x -> catC[b][row][0..256) bf16 pixel-major.
// Block: 64 hw (one image row) x 64 ci tile via LDS.
// ---------------------------------------------------------------------------
__global__ __launch_bounds__(256) void cat_fx(
    const float* __restrict__ fx, unsigned short* __restrict__ catC) {
  int j0 = blockIdx.x * 64;
  int ci0 = blockIdx.y * 64;
  int b = blockIdx.z;
  int tid = threadIdx.x;
  __shared__ unsigned short tile[64][66];

  for (int u = tid; u < 4096; u += 256) {
    int cl = u >> 6, hw_l = u & 63;
    tile[cl][hw_l] = f2bf(fx[((size_t)(b * Cn + ci0 + cl)) * HWn + j0 + hw_l]);
  }
  __syncthreads();
  for (int u = tid; u < 4096; u += 256) {
    int hw_l = u >> 6, cl = u & 63;
    catC[((size_t)b * ROWS + PADR + j0 + hw_l) * 512 + ci0 + cl] = tile[cl][hw_l];
  }
}

// ---------------------------------------------------------------------------
// K5: fused gather: catC[b][row][256..512) = bf16(v[b][c][arg[b,j]]).
// blockIdx.x == 16 blocks zero the pad rows (re-poisoned every call!).
// ---------------------------------------------------------------------------
__global__ __launch_bounds__(256) void gather_cat(
    const float* __restrict__ v, const int* __restrict__ argb,
    unsigned short* __restrict__ catC) {
  int b = blockIdx.y;
  int tid = threadIdx.x;
  if (blockIdx.x == 16) {  // zero pads: rows [0,PADR) and [PADR+HWn, ROWS)
    for (int u = tid; u < 2 * PADR * 512; u += 256) {
      int r = u >> 9;
      int rr = (r < PADR) ? r : (HWn + r);
      catC[((size_t)b * ROWS + rr) * 512 + (u & 511)] = 0;
    }
    return;
  }
  int j = blockIdx.x * 256 + tid;
  int aj = argb[(size_t)b * HWn + j];
  const float* vb = v + (size_t)b * Cn * HWn + aj;
  unsigned short* dst = catC + ((size_t)b * ROWS + PADR + j) * 512 + 256;
#pragma unroll 4
  for (int c = 0; c < Cn; ++c) dst[c] = f2bf(vb[(size_t)c * HWn]);
}

// ---------------------------------------------------------------------------
// K6: conv3x3 as implicit GEMM on MFMA bf16 + epilogue.
// GEMM: D[o][pix] = sum_k A[o][k] * B[k][pix],  K = 9 taps x 512 ci.
// Block tile: 64 o x 128 pix; 4 waves in 2x2 (wave = 32 o x 64 pix,
// 2x4 frags of 16x16x32). Staging via global_load_lds width=16.
// y-OOB handled by catC zero pads; x-edge wrap handled by zeroing the
// affected B-frag pixel columns at read time.
// ---------------------------------------------------------------------------
__global__ __launch_bounds__(256) void conv_mfma(
    const unsigned short* __restrict__ catC, const unsigned short* __restrict__ Wfb,
    const float* __restrict__ bf, const float* __restrict__ star,
    const float* __restrict__ fx, float* __restrict__ out) {
  int m0 = blockIdx.x * 128;   // pixel tile
  int o0 = blockIdx.y * 64;    // output-channel tile
  int b = blockIdx.z;
  int tid = threadIdx.x;
  int lane = tid & 63;
  int wv = tid >> 6;
  int wm = wv >> 1;            // o half (0..1)
  int wn = wv & 1;             // pix half (0..1)

  __shared__ __align__(16) unsigned short AS[64 * 32];    // [o][k]  4 KB
  __shared__ __align__(16) unsigned short BS[128 * 32];   // [pix][k] 8 KB

  floatx4 acc[2][4];
#pragma unroll
  for (int im = 0; im < 2; ++im)
#pragma unroll
    for (int in = 0; in < 4; ++in) acc[im][in] = (floatx4)0.0f;

  const int lq = lane >> 4;     // quad 0..3
  const int lm = lane & 15;
  const bool lane_first = (lm == 0);
  const bool lane_last = (lm == 15);

  // per-lane pieces of staging addresses
  const int srow = lane >> 2;   // 0..15
  const int schunk = (lane & 3) * 8;  // element offset of 16B chunk

  for (int tap = 0; tap < 9; ++tap) {
    int dy = tap / 3 - 1, dx = tap % 3 - 1;
    const unsigned short* bg =
        catC + ((size_t)b * ROWS + PADR + m0 + dy * 64 + dx) * 512;
    const unsigned short* ag = Wfb + ((size_t)tap * 256 + o0) * 512;
    int killsel = dx;  // -1: zero col0 of in==0 ; +1: zero col15 of in==3

    for (int kc = 0; kc < 512; kc += 32) {
      __syncthreads();
      // stage A: 64 rows x 64B ; wave wv covers rows 16wv..16wv+15
      gl_lds16(ag + ((size_t)(wv * 16 + srow)) * 512 + kc + schunk,
               &AS[(wv * 16) * 32]);
      // stage B: 128 rows x 64B ; wave wv covers rows 32wv..32wv+31
#pragma unroll
      for (int i = 0; i < 2; ++i) {
        int r0 = wv * 32 + i * 16;
        gl_lds16(bg + ((size_t)(r0 + srow)) * 512 + kc + schunk,
                 &BS[r0 * 32]);
      }
      __syncthreads();

      bf16x8 afr[2];
#pragma unroll
      for (int im = 0; im < 2; ++im)
        afr[im] = *reinterpret_cast<const bf16x8*>(
            &AS[(wm * 32 + im * 16 + lm) * 32 + lq * 8]);

#pragma unroll
      for (int in = 0; in < 4; ++in) {
        u16x8 braw = *reinterpret_cast<const u16x8*>(
            &BS[(wn * 64 + in * 16 + lm) * 32 + lq * 8]);
        if ((killsel == -1 && in == 0 && lane_first) ||
            (killsel == 1 && in == 3 && lane_last))
          braw = (u16x8)(unsigned short)0;
        union { u16x8 u; bf16x8 h; } cvt; cvt.u = braw;
#pragma unroll
        for (int im = 0; im < 2; ++im)
          acc[im][in] = __builtin_amdgcn_mfma_f32_16x16x32_bf16(
              afr[im], cvt.h, acc[im][in], 0, 0, 0);
      }
    }
  }

  // epilogue: out = fx + (conv + bf) * S
#pragma unroll
  for (int in = 0; in < 4; ++in) {
    int p = m0 + wn * 64 + in * 16 + lm;
    float Sp = star[(size_t)b * HWn + p];
#pragma unroll
    for (int im = 0; im < 2; ++im) {
      int ob = o0 + wm * 32 + im * 16 + lq * 4;
#pragma unroll
      for (int r = 0; r < 4; ++r) {
        int o = ob + r;
        size_t idx = ((size_t)(b * Cn + o)) * HWn + p;
        out[idx] = fx[idx] + (acc[im][in][r] + bf[o]) * Sp;
      }
    }
  }
}

// ---------------------------------------------------------------------------
extern "C" void kernel_launch(void* const* d_in, const int* in_sizes, int n_in,
                              void* d_out, int out_size, void* d_ws, size_t ws_size,
                              hipStream_t stream) {
  const float* front_x   = (const float*)d_in[0];
  const float* cross_x   = (const float*)d_in[1];
  const float* front_hat = (const float*)d_in[2];
  const float* Wq = (const float*)d_in[3];
  const float* bq = (const float*)d_in[4];
  const float* Wk = (const float*)d_in[5];
  const float* bk = (const float*)d_in[6];
  const float* Wv = (const float*)d_in[7];
  const float* bv = (const float*)d_in[8];
  const float* Wf = (const float*)d_in[9];
  const float* bf = (const float*)d_in[10];
  float* out = (float*)d_out;

  char* ws = (char*)d_ws;
  size_t off = 0;
  auto alloc = [&](size_t bytes) -> void* {
    void* p = (void*)(ws + off);
    off += (bytes + 255) & ~(size_t)255;
    return p;
  };
  double* Wqt = (double*)alloc(8192 * sizeof(double));
  double* Wkt = (double*)alloc(8192 * sizeof(double));
  double* bqd = (double*)alloc(32 * sizeof(double));
  double* bkd = (double*)alloc(32 * sizeof(double));
  float*  Wvt = (float*)alloc(65536 * sizeof(float));
  unsigned short* Wfb = (unsigned short*)alloc((size_t)9 * 256 * 512 * sizeof(unsigned short));
  double* qd  = (double*)alloc((size_t)Bn * HWn * C8 * sizeof(double));
  double* kd  = (double*)alloc((size_t)Bn * HWn * C8 * sizeof(double));
  float*  star = (float*)alloc((size_t)Bn * HWn * sizeof(float));
  int*    argb = (int*)alloc((size_t)Bn * HWn * sizeof(int));
  float*  v    = (float*)alloc((size_t)Bn * Cn * HWn * sizeof(float));
  unsigned short* catC = (unsigned short*)alloc((size_t)Bn * ROWS * 512 * sizeof(unsigned short));
  // total ~45 MB

  prep_w<<<dim3((9 * 256 * 512 + 255) / 256), dim3(256), 0, stream>>>(
      Wq, bq, Wk, bk, Wv, Wf, Wqt, bqd, Wkt, bkd, Wvt, Wfb);

  proj_qk<<<dim3(HWn / 256, Bn, 2), dim3(256), 0, stream>>>(
      cross_x, front_x, Wqt, bqd, Wkt, bkd, qd, kd);

  energy_max<<<dim3(HWn / 64, Bn), dim3(512), 0, stream>>>(qd, kd, star, argb);

  proj_v<<<dim3(HWn / 256, Bn, 4), dim3(256), 0, stream>>>(front_hat, Wvt, bv, v);

  cat_fx<<<dim3(HWn / 64, Cn / 64, Bn), dim3(256), 0, stream>>>(front_x, catC);

  gather_cat<<<dim3(HWn / 256 + 1, Bn), dim3(256), 0, stream>>>(v, argb, catC);

  conv_mfma<<<dim3(HWn / 128, Cn / 64, Bn), dim3(256), 0, stream>>>(
      catC, Wfb, bf, star, front_x, out);
}

// Round 3
// 656.592 us; speedup vs baseline: 2.7548x; 1.0390x over previous
//
#include <hip/hip_runtime.h>

#define Bn 4
#define Cn 256
#define C8 32
#define Hn 64
#define Wn 64
#define HWn 4096
#define PADR 66
#define ROWS (HWn + 2 * PADR)   // 4228 padded pixel-rows per batch
#define MARGIN 3e-2f

typedef __bf16 bf16x8 __attribute__((ext_vector_type(8)));
typedef float floatx4 __attribute__((ext_vector_type(4)));
typedef unsigned short u16x8 __attribute__((ext_vector_type(8)));

__device__ __forceinline__ unsigned short f2bf(float f) {
  union { float f; unsigned int u; } c; c.f = f;
  unsigned int u = c.u;
  return (unsigned short)((u + 0x7FFFu + ((u >> 16) & 1u)) >> 16);  // RNE
}
__device__ __forceinline__ float bf2f(unsigned short h) {
  union { unsigned int u; float f; } c; c.u = ((unsigned int)h) << 16;
  return c.f;
}
__device__ __forceinline__ void gl_lds16(const void* g, void* l) {
  __builtin_amdgcn_global_load_lds(
      (__attribute__((address_space(1))) void*)(uintptr_t)g,
      (__attribute__((address_space(3))) void*)(uintptr_t)l, 16, 0, 0);
}

// ---------------------------------------------------------------------------
// K0: weight prep (unchanged).
// ---------------------------------------------------------------------------
__global__ void prep_w(const float* __restrict__ Wq, const float* __restrict__ bq,
                       const float* __restrict__ Wk, const float* __restrict__ bk,
                       const float* __restrict__ Wv, const float* __restrict__ Wf,
                       double* __restrict__ Wqt, double* __restrict__ bqd,
                       double* __restrict__ Wkt, double* __restrict__ bkd,
                       float* __restrict__ Wvt, unsigned short* __restrict__ Wfb) {
  size_t t = (size_t)blockIdx.x * 256 + threadIdx.x;
  if (t < 8192) {
    int o = (int)(t / 256), c = (int)(t % 256);
    Wqt[(size_t)c * 32 + o] = (double)Wq[t];
    Wkt[(size_t)c * 32 + o] = (double)Wk[t];
  }
  if (t < 32) { bqd[t] = (double)bq[t]; bkd[t] = (double)bk[t]; }
  if (t < 65536) {
    int o = (int)(t / 256), c = (int)(t % 256);
    Wvt[(size_t)c * 256 + o] = Wv[t];
  }
  if (t < (size_t)9 * 256 * 512) {
    int tap = (int)(t / (256 * 512));
    int rem = (int)(t % (256 * 512));
    int o = rem / 512, ci = rem % 512;
    Wfb[t] = f2bf(Wf[((size_t)o * 512 + ci) * 9 + tap]);
  }
}

// ---------------------------------------------------------------------------
// K1: q/k projection in fp64 + bf16 hi/lo split outputs for the MFMA energy.
// ---------------------------------------------------------------------------
__global__ __launch_bounds__(256) void proj_qk(
    const float* __restrict__ cross_x, const float* __restrict__ front_x,
    const double* __restrict__ Wqt, const double* __restrict__ bqd,
    const double* __restrict__ Wkt, const double* __restrict__ bkd,
    double* __restrict__ qd, double* __restrict__ kd,
    unsigned short* __restrict__ qhi, unsigned short* __restrict__ qlo,
    unsigned short* __restrict__ khi, unsigned short* __restrict__ klo) {
  int j = blockIdx.x * 256 + threadIdx.x;
  int b = blockIdx.y;
  int z = blockIdx.z;
  const float* x = (z == 0) ? cross_x : front_x;
  const double* Wt = (z == 0) ? Wqt : Wkt;
  const double* bd = (z == 0) ? bqd : bkd;
  double* outp = (z == 0) ? qd : kd;
  unsigned short* hip_ = (z == 0) ? qhi : khi;
  unsigned short* lop_ = (z == 0) ? qlo : klo;

  const float* xb = x + (size_t)b * Cn * HWn + j;
  double acc[C8];
#pragma unroll
  for (int o = 0; o < C8; ++o) acc[o] = bd[o];
  for (int c = 0; c < Cn; ++c) {
    double xv = (double)xb[(size_t)c * HWn];
    const double* wrow = Wt + (size_t)c * C8;
#pragma unroll
    for (int o = 0; o < C8; ++o) acc[o] += wrow[o] * xv;
  }
  double* op = outp + ((size_t)b * HWn + j) * C8;
  unsigned short* hp = hip_ + ((size_t)b * HWn + j) * C8;
  unsigned short* lp = lop_ + ((size_t)b * HWn + j) * C8;
#pragma unroll
  for (int o = 0; o < C8; ++o) {
    op[o] = acc[o];
    float f = (float)acc[o];
    unsigned short h = f2bf(f);
    hp[o] = h;
    lp[o] = f2bf(f - bf2f(h));
  }
}

// ---------------------------------------------------------------------------
// K2: approximate energy via split-bf16 MFMA, fused max/top2/argmax.
// Block: 256 thr (4 waves). Wave wv owns j-subtile j0+16*wv..+15 (B-frags in
// regs, loaded once); i loops over 4096 in 64-row LDS stages (A-frags).
// Per 16x16 tile: acc = kh*qh + kh*ql + kl*qh (one MFMA each, K=32).
// Near-ties (b1-b2 < MARGIN) -> flag -> exact fp64 recheck kernel.
// ---------------------------------------------------------------------------
__global__ __launch_bounds__(256) void energy_approx(
    const unsigned short* __restrict__ khi, const unsigned short* __restrict__ klo,
    const unsigned short* __restrict__ qhi, const unsigned short* __restrict__ qlo,
    float* __restrict__ star, int* __restrict__ argb, int* __restrict__ flag) {
  int b = blockIdx.y;
  int j0 = blockIdx.x * 64;
  int tid = threadIdx.x;
  int lane = tid & 63, wv = tid >> 6;
  int lm = lane & 15, lq = lane >> 4;

  __shared__ __align__(16) unsigned short AH[64 * 32];
  __shared__ __align__(16) unsigned short AL[64 * 32];

  int j = j0 + wv * 16 + lm;
  bf16x8 qh = *reinterpret_cast<const bf16x8*>(qhi + ((size_t)b * HWn + j) * 32 + lq * 8);
  bf16x8 ql = *reinterpret_cast<const bf16x8*>(qlo + ((size_t)b * HWn + j) * 32 + lq * 8);

  float b1 = -3.0e38f, b2 = -3.0e38f;
  int i1 = 0;
  const int srow = lane >> 2, soff = (lane & 3) * 8;

  for (int it = 0; it < HWn; it += 64) {
    __syncthreads();
    gl_lds16(khi + ((size_t)b * HWn + it + wv * 16 + srow) * 32 + soff,
             &AH[(wv * 16) * 32]);
    gl_lds16(klo + ((size_t)b * HWn + it + wv * 16 + srow) * 32 + soff,
             &AL[(wv * 16) * 32]);
    __syncthreads();
#pragma unroll
    for (int sub = 0; sub < 4; ++sub) {
      bf16x8 ah = *reinterpret_cast<const bf16x8*>(&AH[(sub * 16 + lm) * 32 + lq * 8]);
      bf16x8 al = *reinterpret_cast<const bf16x8*>(&AL[(sub * 16 + lm) * 32 + lq * 8]);
      floatx4 acc = (floatx4)0.0f;
      acc = __builtin_amdgcn_mfma_f32_16x16x32_bf16(ah, qh, acc, 0, 0, 0);
      acc = __builtin_amdgcn_mfma_f32_16x16x32_bf16(ah, ql, acc, 0, 0, 0);
      acc = __builtin_amdgcn_mfma_f32_16x16x32_bf16(al, qh, acc, 0, 0, 0);
      float m4 = fmaxf(fmaxf(acc[0], acc[1]), fmaxf(acc[2], acc[3]));
      if (m4 > b1) {  // rare after warm-up: exact top-2 maintenance
        int ib = it + sub * 16 + lq * 4;
#pragma unroll
        for (int r = 0; r < 4; ++r) {
          float s = acc[r];
          if (s > b1) { b2 = b1; b1 = s; i1 = ib + r; }
          else b2 = fmaxf(b2, s);
        }
      } else {
        b2 = fmaxf(b2, m4);
      }
    }
  }
  // merge the 4 quads holding the same j (lanes lm, lm+16, lm+32, lm+48)
#pragma unroll
  for (int m = 16; m <= 32; m <<= 1) {
    float ob1 = __shfl_xor(b1, m, 64);
    int oi1 = __shfl_xor(i1, m, 64);
    float ob2 = __shfl_xor(b2, m, 64);
    float c2;
    if (ob1 > b1 || (ob1 == b1 && oi1 < i1)) {
      c2 = fmaxf(b1, ob2);
      b1 = ob1; i1 = oi1;
    } else {
      c2 = fmaxf(ob1, b2);
    }
    b2 = c2;
  }
  if (lq == 0) {
    size_t o = (size_t)b * HWn + j;
    star[o] = b1;
    argb[o] = i1;
    flag[o] = (b1 - b2 < MARGIN) ? 1 : 0;
  }
}

// ---------------------------------------------------------------------------
// K3: exact fp64 recheck for flagged (near-tie) queries. One wave per query;
// nearly all waves exit after one load.
// ---------------------------------------------------------------------------
__global__ __launch_bounds__(256) void recheck(
    const double* __restrict__ qd, const double* __restrict__ kd,
    const int* __restrict__ flag, float* __restrict__ star, int* __restrict__ argb) {
  int b = blockIdx.y;
  int j = blockIdx.x * 4 + (threadIdx.x >> 6);
  int lane = threadIdx.x & 63;
  if (!flag[(size_t)b * HWn + j]) return;
  const double* qp = qd + ((size_t)b * HWn + j) * 32;
  double qj[32];
#pragma unroll
  for (int o = 0; o < 32; ++o) qj[o] = qp[o];
  double best = -1.0e300;
  int bi = 0;
  for (int i = lane; i < HWn; i += 64) {
    const double* kp = kd + ((size_t)b * HWn + i) * 32;
    double s = 0.0;
#pragma unroll
    for (int o = 0; o < 32; ++o) s += kp[o] * qj[o];
    if (s > best) { best = s; bi = i; }
  }
#pragma unroll
  for (int m = 1; m < 64; m <<= 1) {
    double ob = __shfl_xor(best, m, 64);
    int oi = __shfl_xor(bi, m, 64);
    if (ob > best || (ob == best && oi < bi)) { best = ob; bi = oi; }
  }
  if (lane == 0) {
    star[(size_t)b * HWn + j] = (float)best;
    argb[(size_t)b * HWn + j] = bi;
  }
}

// ---------------------------------------------------------------------------
// K4: v projection fp32 (unchanged).
// ---------------------------------------------------------------------------
__global__ __launch_bounds__(256) void proj_v(
    const float* __restrict__ x, const float* __restrict__ Wvt,
    const float* __restrict__ bv, float* __restrict__ v) {
  int j = blockIdx.x * 256 + threadIdx.x;
  int b = blockIdx.y;
  int o0 = blockIdx.z * 64;
  const float* xb = x + (size_t)b * Cn * HWn + j;
  float acc[64];
#pragma unroll
  for (int o = 0; o < 64; ++o) acc[o] = bv[o0 + o];
  for (int c = 0; c < Cn; ++c) {
    float xv = xb[(size_t)c * HWn];
    const float* wrow = Wvt + (size_t)c * 256 + o0;
#pragma unroll
    for (int o = 0; o < 64; ++o) acc[o] += wrow[o] * xv;
  }
  float* vp = v + ((size_t)b * Cn + o0) * HWn + j;
#pragma unroll
  for (int o = 0; o < 64; ++o) vp[(size_t)o * HWn] = acc[o];
}

// ---------------------------------------------------------------------------
// K5: transpose front_x -> catC[b][row][0..256) bf16 pixel-major (unchanged).
// ---------------------------------------------------------------------------
__global__ __launch_bounds__(256) void cat_fx(
    const float* __restrict__ fx, unsigned short* __restrict__ catC) {
  int j0 = blockIdx.x * 64;
  int ci0 = blockIdx.y * 64;
  int b = blockIdx.z;
  int tid = threadIdx.x;
  __shared__ unsigned short tile[64][66];

  for (int u = tid; u < 4096; u += 256) {
    int cl = u >> 6, hw_l = u & 63;
    tile[cl][hw_l] = f2bf(fx[((size_t)(b * Cn + ci0 + cl)) * HWn + j0 + hw_l]);
  }
  __syncthreads();
  for (int u = tid; u < 4096; u += 256) {
    int hw_l = u >> 6, cl = u & 63;
    catC[((size_t)b * ROWS + PADR + j0 + hw_l) * 512 + ci0 + cl] = tile[cl][hw_l];
  }
}

// ---------------------------------------------------------------------------
// K6: gather into catC upper channels + zero pad rows (unchanged).
// ---------------------------------------------------------------------------
__global__ __launch_bounds__(256) void gather_cat(
    const float* __restrict__ v, const int* __restrict__ argb,
    unsigned short* __restrict__ catC) {
  int b = blockIdx.y;
  int tid = threadIdx.x;
  if (blockIdx.x == 16) {
    for (int u = tid; u < 2 * PADR * 512; u += 256) {
      int r = u >> 9;
      int rr = (r < PADR) ? r : (HWn + r);
      catC[((size_t)b * ROWS + rr) * 512 + (u & 511)] = 0;
    }
    return;
  }
  int j = blockIdx.x * 256 + tid;
  int aj = argb[(size_t)b * HWn + j];
  const float* vb = v + (size_t)b * Cn * HWn + aj;
  unsigned short* dst = catC + ((size_t)b * ROWS + PADR + j) * 512 + 256;
#pragma unroll 4
  for (int c = 0; c < Cn; ++c) dst[c] = f2bf(vb[(size_t)c * HWn]);
}

// ---------------------------------------------------------------------------
// K7: conv3x3 implicit GEMM on MFMA bf16 + epilogue. Block tile 128o x 128pix,
// wave tile 64o x 64pix (4x4 frags) -> 16 MFMA per 8 ds_read_b128.
// ---------------------------------------------------------------------------
__global__ __launch_bounds__(256) void conv_mfma(
    const unsigned short* __restrict__ catC, const unsigned short* __restrict__ Wfb,
    const float* __restrict__ bf, const float* __restrict__ star,
    const float* __restrict__ fx, float* __restrict__ out) {
  int m0 = blockIdx.x * 128;   // pixel tile
  int o0 = blockIdx.y * 128;   // output-channel tile
  int b = blockIdx.z;
  int tid = threadIdx.x;
  int lane = tid & 63;
  int wv = tid >> 6;
  int wm = wv >> 1;            // o half
  int wn = wv & 1;             // pix half
  int lm = lane & 15, lq = lane >> 4;
  const bool lane_first = (lm == 0);
  const bool lane_last = (lm == 15);

  __shared__ __align__(16) unsigned short AS[128 * 32];   // [o][k]   8 KB
  __shared__ __align__(16) unsigned short BS[128 * 32];   // [pix][k] 8 KB

  floatx4 acc[4][4];
#pragma unroll
  for (int im = 0; im < 4; ++im)
#pragma unroll
    for (int in = 0; in < 4; ++in) acc[im][in] = (floatx4)0.0f;

  const int srow = lane >> 2, soff = (lane & 3) * 8;

  for (int tap = 0; tap < 9; ++tap) {
    int dy = tap / 3 - 1, dx = tap % 3 - 1;
    const unsigned short* bg =
        catC + ((size_t)b * ROWS + PADR + m0 + dy * 64 + dx) * 512;
    const unsigned short* ag = Wfb + ((size_t)tap * 256 + o0) * 512;
    int killsel = dx;

    for (int kc = 0; kc < 512; kc += 32) {
      __syncthreads();
#pragma unroll
      for (int i = 0; i < 2; ++i) {
        int r0 = wv * 32 + i * 16;
        gl_lds16(ag + ((size_t)(r0 + srow)) * 512 + kc + soff, &AS[r0 * 32]);
        gl_lds16(bg + ((size_t)(r0 + srow)) * 512 + kc + soff, &BS[r0 * 32]);
      }
      __syncthreads();

      bf16x8 afr[4];
#pragma unroll
      for (int im = 0; im < 4; ++im)
        afr[im] = *reinterpret_cast<const bf16x8*>(
            &AS[(wm * 64 + im * 16 + lm) * 32 + lq * 8]);

#pragma unroll
      for (int in = 0; in < 4; ++in) {
        u16x8 braw = *reinterpret_cast<const u16x8*>(
            &BS[(wn * 64 + in * 16 + lm) * 32 + lq * 8]);
        if ((killsel == -1 && in == 0 && lane_first) ||
            (killsel == 1 && in == 3 && lane_last))
          braw = (u16x8)(unsigned short)0;
        union { u16x8 u; bf16x8 h; } cvt; cvt.u = braw;
#pragma unroll
        for (int im = 0; im < 4; ++im)
          acc[im][in] = __builtin_amdgcn_mfma_f32_16x16x32_bf16(
              afr[im], cvt.h, acc[im][in], 0, 0, 0);
      }
    }
  }

#pragma unroll
  for (int in = 0; in < 4; ++in) {
    int p = m0 + wn * 64 + in * 16 + lm;
    float Sp = star[(size_t)b * HWn + p];
#pragma unroll
    for (int im = 0; im < 4; ++im) {
      int ob = o0 + wm * 64 + im * 16 + lq * 4;
#pragma unroll
      for (int r = 0; r < 4; ++r) {
        int o = ob + r;
        size_t idx = ((size_t)(b * Cn + o)) * HWn + p;
        out[idx] = fx[idx] + (acc[im][in][r] + bf[o]) * Sp;
      }
    }
  }
}

// ---------------------------------------------------------------------------
extern "C" void kernel_launch(void* const* d_in, const int* in_sizes, int n_in,
                              void* d_out, int out_size, void* d_ws, size_t ws_size,
                              hipStream_t stream) {
  const float* front_x   = (const float*)d_in[0];
  const float* cross_x   = (const float*)d_in[1];
  const float* front_hat = (const float*)d_in[2];
  const float* Wq = (const float*)d_in[3];
  const float* bq = (const float*)d_in[4];
  const float* Wk = (const float*)d_in[5];
  const float* bk = (const float*)d_in[6];
  const float* Wv = (const float*)d_in[7];
  const float* bv = (const float*)d_in[8];
  const float* Wf = (const float*)d_in[9];
  const float* bf = (const float*)d_in[10];
  float* out = (float*)d_out;

  char* ws = (char*)d_ws;
  size_t off = 0;
  auto alloc = [&](size_t bytes) -> void* {
    void* p = (void*)(ws + off);
    off += (bytes + 255) & ~(size_t)255;
    return p;
  };
  double* Wqt = (double*)alloc(8192 * sizeof(double));
  double* Wkt = (double*)alloc(8192 * sizeof(double));
  double* bqd = (double*)alloc(32 * sizeof(double));
  double* bkd = (double*)alloc(32 * sizeof(double));
  float*  Wvt = (float*)alloc(65536 * sizeof(float));
  unsigned short* Wfb = (unsigned short*)alloc((size_t)9 * 256 * 512 * sizeof(unsigned short));
  double* qd  = (double*)alloc((size_t)Bn * HWn * C8 * sizeof(double));
  double* kd  = (double*)alloc((size_t)Bn * HWn * C8 * sizeof(double));
  unsigned short* qhi = (unsigned short*)alloc((size_t)Bn * HWn * C8 * 2);
  unsigned short* qlo = (unsigned short*)alloc((size_t)Bn * HWn * C8 * 2);
  unsigned short* khi = (unsigned short*)alloc((size_t)Bn * HWn * C8 * 2);
  unsigned short* klo = (unsigned short*)alloc((size_t)Bn * HWn * C8 * 2);
  float*  star = (float*)alloc((size_t)Bn * HWn * sizeof(float));
  int*    argb = (int*)alloc((size_t)Bn * HWn * sizeof(int));
  int*    flg  = (int*)alloc((size_t)Bn * HWn * sizeof(int));
  float*  v    = (float*)alloc((size_t)Bn * Cn * HWn * sizeof(float));
  unsigned short* catC = (unsigned short*)alloc((size_t)Bn * ROWS * 512 * sizeof(unsigned short));

  prep_w<<<dim3((9 * 256 * 512 + 255) / 256), dim3(256), 0, stream>>>(
      Wq, bq, Wk, bk, Wv, Wf, Wqt, bqd, Wkt, bkd, Wvt, Wfb);

  proj_qk<<<dim3(HWn / 256, Bn, 2), dim3(256), 0, stream>>>(
      cross_x, front_x, Wqt, bqd, Wkt, bkd, qd, kd, qhi, qlo, khi, klo);

  energy_approx<<<dim3(HWn / 64, Bn), dim3(256), 0, stream>>>(
      khi, klo, qhi, qlo, star, argb, flg);

  recheck<<<dim3(HWn / 4, Bn), dim3(256), 0, stream>>>(qd, kd, flg, star, argb);

  proj_v<<<dim3(HWn / 256, Bn, 4), dim3(256), 0, stream>>>(front_hat, Wvt, bv, v);

  cat_fx<<<dim3(HWn / 64, Cn / 64, Bn), dim3(256), 0, stream>>>(front_x, catC);

  gather_cat<<<dim3(HWn / 256 + 1, Bn), dim3(256), 0, stream>>>(v, argb, catC);

  conv_mfma<<<dim3(HWn / 128, Cn / 128, Bn), dim3(256), 0, stream>>>(
      catC, Wfb, bf, star, front_x, out);
}